// Round 10
// baseline (272.790 us; speedup 1.0000x reference)
//
#include <hip/hip_runtime.h>
#include <hip/hip_bf16.h>

typedef __bf16 bf16;
typedef __bf16 bf16x8 __attribute__((ext_vector_type(8)));
typedef float f32x4 __attribute__((ext_vector_type(4)));

#define LL 1024
#define SS 1024
#define BB 4
#define EE 1024
#define HH 16
#define MM 256
#define HD 64
#define BH 64

__device__ __forceinline__ f32x4 mfma16(bf16x8 a, bf16x8 b, f32x4 c) {
  return __builtin_amdgcn_mfma_f32_16x16x32_bf16(a, b, c, 0, 0, 0);
}

__device__ __forceinline__ void gload_lds16(const bf16* g, bf16* l) {
  __builtin_amdgcn_global_load_lds(
      (const __attribute__((address_space(1))) unsigned int*)(g),
      (__attribute__((address_space(3))) unsigned int*)(l), 16, 0, 0);
}

// load 8 contiguous f32 (32B-aligned) -> bf16x8 fragment
__device__ __forceinline__ bf16x8 cvt8(const float* p) {
  const f32x4 lo = *reinterpret_cast<const f32x4*>(p);
  const f32x4 hi = *reinterpret_cast<const f32x4*>(p + 4);
  bf16x8 r;
  r[0] = (bf16)lo[0]; r[1] = (bf16)lo[1]; r[2] = (bf16)lo[2]; r[3] = (bf16)lo[3];
  r[4] = (bf16)hi[0]; r[5] = (bf16)hi[1]; r[6] = (bf16)hi[2]; r[7] = (bf16)hi[3];
  return r;
}

// fused f32->bf16 conversion over six regions + vmT transpose (bid >= 8704)
__global__ __launch_bounds__(256) void cvt_all_kernel(
    const float* __restrict__ ipw, const float* __restrict__ opw,
    const float* __restrict__ k_mem, const float* __restrict__ query,
    const float* __restrict__ key_i, const float* __restrict__ value,
    const float* __restrict__ v_mem,
    bf16* __restrict__ wb, bf16* __restrict__ opwb, bf16* __restrict__ kmemb,
    bf16* __restrict__ xq, bf16* __restrict__ xk, bf16* __restrict__ xv,
    bf16* __restrict__ vmT) {
  const int bid = blockIdx.x, tid = threadIdx.x;
  if (bid >= 8704) {  // vmT[bh][d][m] = v_mem[m][b][h*64+d]
    const int bh = bid - 8704;
    const int b = bh >> 4, h = bh & 15;
    const int d = tid & 63;
    const int mo = tid >> 6;
    for (int m = mo; m < MM; m += 4) {
      float v = v_mem[((size_t)m * BB + b) * EE + h * 64 + d];
      vmT[((size_t)bh * HD + d) * MM + m] = (bf16)v;
    }
    return;
  }
  const float* src; bf16* dst; int base;
  if (bid < 1536)      { src = ipw;   dst = wb;    base = 0; }
  else if (bid < 2048) { src = opw;   dst = opwb;  base = 1536; }
  else if (bid < 2560) { src = k_mem; dst = kmemb; base = 2048; }
  else if (bid < 4608) { src = query; dst = xq;    base = 2560; }
  else if (bid < 6656) { src = key_i; dst = xk;    base = 4608; }
  else                 { src = value; dst = xv;    base = 6656; }
  const size_t i = ((size_t)(bid - base) * 256 + tid) * 8;
  *reinterpret_cast<bf16x8*>(dst + i) = cvt8(src + i);
}

// ---------------------------------------------------------------------------
// In-place interleaved rotary on qh and kh (pure HBM-bound elementwise).
// ---------------------------------------------------------------------------
__global__ __launch_bounds__(256) void rope_kernel(
    bf16* __restrict__ qh, bf16* __restrict__ kh,
    const float* __restrict__ q_pe, const float* __restrict__ kv_pe) {
  const size_t CP = (size_t)BH * LL * HD / 8;  // 524288 chunks per tensor
  size_t gi = (size_t)blockIdx.x * 256 + threadIdx.x;
  bf16* x; const float* pe;
  if (gi < CP) { x = qh; pe = q_pe; }
  else         { x = kh; pe = kv_pe; gi -= CP; }
  const int d8 = gi & 7;
  const int t  = (int)((gi >> 3) & (LL - 1));
  const int bh = (int)(gi >> 13);
  const int b = bh >> 4, h = bh & 15;
  bf16* xp = x + gi * 8;
  const float* pp = pe + (((size_t)b * LL + t) * EE + h * 64 + d8 * 8) * 2;
  bf16x8 v = *reinterpret_cast<const bf16x8*>(xp);
  const f32x4 p0 = *reinterpret_cast<const f32x4*>(pp);
  const f32x4 p1 = *reinterpret_cast<const f32x4*>(pp + 4);
  const f32x4 p2 = *reinterpret_cast<const f32x4*>(pp + 8);
  const f32x4 p3 = *reinterpret_cast<const f32x4*>(pp + 12);
  float cs[8], sn[8], xv[8];
  cs[0]=p0[0]; sn[0]=p0[1]; cs[1]=p0[2]; sn[1]=p0[3];
  cs[2]=p1[0]; sn[2]=p1[1]; cs[3]=p1[2]; sn[3]=p1[3];
  cs[4]=p2[0]; sn[4]=p2[1]; cs[5]=p2[2]; sn[5]=p2[3];
  cs[6]=p3[0]; sn[6]=p3[1]; cs[7]=p3[2]; sn[7]=p3[3];
#pragma unroll
  for (int j = 0; j < 8; ++j) xv[j] = (float)v[j];
  bf16x8 o;
#pragma unroll
  for (int j = 0; j < 8; j += 2) {
    o[j]     = (bf16)(xv[j]     * cs[j]     - xv[j + 1] * sn[j]);
    o[j + 1] = (bf16)(xv[j + 1] * cs[j + 1] + xv[j]     * sn[j + 1]);
  }
  *reinterpret_cast<bf16x8*>(xp) = o;
}

// ---------------------------------------------------------------------------
// Fused q/k/v projection GEMM (r8 proven config): BM=BN=128, 768 blocks,
// 4 waves 2x2, double-buffered LDS, global_load_lds w=16.
// ---------------------------------------------------------------------------
__global__ __launch_bounds__(256) void gemm3_kernel(
    const bf16* __restrict__ xq, const bf16* __restrict__ xk,
    const bf16* __restrict__ xv, const bf16* __restrict__ wb,
    const float* __restrict__ ipb, bf16* __restrict__ qh,
    bf16* __restrict__ kh, bf16* __restrict__ vhT) {
  __shared__ bf16 As[2][4096];
  __shared__ bf16 Bs[2][4096];
  const int tid = threadIdx.x;
  const int wv = tid >> 6, lane = tid & 63;
  const int lrow = lane & 15, lkg = lane >> 4;
  const int wr = wv >> 1, wc = wv & 1;
  const int n = (blockIdx.x & 7) * 96 + (blockIdx.x >> 3);  // XCD-chunked
  const int which = n >> 8, sub = n & 255;
  const int rowt = sub >> 3, colt = sub & 7;
  const int rowA0 = rowt * 128, colB0 = colt * 128;

  const bf16* X = (which == 0) ? xq : (which == 1) ? xk : xv;
  const bf16* W = wb + (size_t)which * EE * EE;

  const f32x4 zero = {0.f, 0.f, 0.f, 0.f};
  f32x4 acc[4][4];
#pragma unroll
  for (int i = 0; i < 4; ++i)
#pragma unroll
    for (int j = 0; j < 4; ++j) acc[i][j] = zero;

  auto stage = [&](int buf, int k0) {
#pragma unroll
    for (int t = 0; t < 2; ++t) {
      const int i = wv * 2 + t;
      const int slot = i * 64 + lane;
      const int srow = slot & 127, sk8 = slot >> 7;
      gload_lds16(X + (size_t)(rowA0 + srow) * EE + k0 + sk8 * 8, &As[buf][i * 512]);
      gload_lds16(W + (size_t)(colB0 + srow) * EE + k0 + sk8 * 8, &Bs[buf][i * 512]);
    }
  };

  stage(0, 0);
  __syncthreads();
  for (int ks = 0; ks < 32; ++ks) {
    const int buf = ks & 1;
    if (ks < 31) stage(buf ^ 1, (ks + 1) * 32);
    bf16x8 av[4], bv[4];
#pragma unroll
    for (int i = 0; i < 4; ++i) {
      av[i] = *reinterpret_cast<const bf16x8*>(&As[buf][lkg * 1024 + (wr * 64 + i * 16 + lrow) * 8]);
      bv[i] = *reinterpret_cast<const bf16x8*>(&Bs[buf][lkg * 1024 + (wc * 64 + i * 16 + lrow) * 8]);
    }
#pragma unroll
    for (int mt = 0; mt < 4; ++mt)
#pragma unroll
      for (int nt = 0; nt < 4; ++nt)
        acc[mt][nt] = mfma16(av[mt], bv[nt], acc[mt][nt]);
    __syncthreads();
  }

#pragma unroll
  for (int nt = 0; nt < 4; ++nt) {
    const int col = colB0 + wc * 64 + nt * 16 + lrow;
    const float bs = ipb[which * EE + col];
    const int h = col >> 6, d = col & 63;
#pragma unroll
    for (int mt = 0; mt < 4; ++mt) {
#pragma unroll
      for (int r = 0; r < 4; ++r) {
        const int rowg = rowA0 + wr * 64 + mt * 16 + lkg * 4 + r;
        const int t = rowg >> 2;
        const int b = rowg & 3;
        float v = acc[mt][nt][r] + bs;
        if (which == 0) v *= 0.125f;
        const int bh = b * HH + h;
        if (which == 2)
          vhT[((size_t)bh * HD + d) * SS + t] = (bf16)v;
        else if (which == 1)
          kh[((size_t)bh * LL + t) * HD + d] = (bf16)v;
        else
          qh[((size_t)bh * LL + t) * HD + d] = (bf16)v;
      }
    }
  }
}

// ---------------------------------------------------------------------------
// Out-projection GEMM: BM=128, BN=64 -> 512 blocks. Writes f32 d_out.
// ---------------------------------------------------------------------------
__global__ __launch_bounds__(256) void gemm_out_kernel(
    const bf16* __restrict__ Xb, const bf16* __restrict__ W,
    const float* __restrict__ bias, float* __restrict__ outf) {
  __shared__ bf16 As[2][4096];
  __shared__ bf16 Bs[2][2048];
  const int tid = threadIdx.x;
  const int wv = tid >> 6, lane = tid & 63;
  const int lrow = lane & 15, lkg = lane >> 4;
  const int wr = wv >> 1, wc = wv & 1;
  const int n = (blockIdx.x & 7) * 64 + (blockIdx.x >> 3);
  const int rowt = n >> 4, colt = n & 15;
  const int rowA0 = rowt * 128, colB0 = colt * 64;

  const f32x4 zero = {0.f, 0.f, 0.f, 0.f};
  f32x4 acc[4][2];
#pragma unroll
  for (int i = 0; i < 4; ++i)
#pragma unroll
    for (int j = 0; j < 2; ++j) acc[i][j] = zero;

  auto stage = [&](int buf, int k0) {
#pragma unroll
    for (int t = 0; t < 2; ++t) {
      const int i = wv * 2 + t;
      const int slot = i * 64 + lane;
      const int srow = slot & 127, sk8 = slot >> 7;
      gload_lds16(Xb + (size_t)(rowA0 + srow) * EE + k0 + sk8 * 8, &As[buf][i * 512]);
    }
    {
      const int slot = wv * 64 + lane;
      const int srow = slot & 63, sk8 = slot >> 6;
      gload_lds16(W + (size_t)(colB0 + srow) * EE + k0 + sk8 * 8, &Bs[buf][wv * 512]);
    }
  };

  stage(0, 0);
  __syncthreads();
  for (int ks = 0; ks < 32; ++ks) {
    const int buf = ks & 1;
    if (ks < 31) stage(buf ^ 1, (ks + 1) * 32);
    bf16x8 av[4], bv[2];
#pragma unroll
    for (int i = 0; i < 4; ++i)
      av[i] = *reinterpret_cast<const bf16x8*>(&As[buf][lkg * 1024 + (wr * 64 + i * 16 + lrow) * 8]);
#pragma unroll
    for (int j = 0; j < 2; ++j)
      bv[j] = *reinterpret_cast<const bf16x8*>(&Bs[buf][lkg * 512 + (wc * 32 + j * 16 + lrow) * 8]);
#pragma unroll
    for (int mt = 0; mt < 4; ++mt)
#pragma unroll
      for (int nt = 0; nt < 2; ++nt)
        acc[mt][nt] = mfma16(av[mt], bv[nt], acc[mt][nt]);
    __syncthreads();
  }

#pragma unroll
  for (int nt = 0; nt < 2; ++nt) {
    const int col = colB0 + wc * 32 + nt * 16 + lrow;
    const float bs = bias[col];
#pragma unroll
    for (int mt = 0; mt < 4; ++mt)
#pragma unroll
      for (int r = 0; r < 4; ++r) {
        const int rowg = rowA0 + wr * 64 + mt * 16 + lkg * 4 + r;
        outf[(size_t)rowg * EE + col] = acc[mt][nt][r] + bs;
      }
  }
}

// ---------------------------------------------------------------------------
// Column softmax stats over L for each (bh, s): moff = m + ln(sum exp(sc-m)).
// ---------------------------------------------------------------------------
__global__ __launch_bounds__(256) void stats_kernel(
    const bf16* __restrict__ qh, const bf16* __restrict__ kh,
    float* __restrict__ moff) {
  __shared__ float sm[4][4][16], sd[4][4][16];
  const int tid = threadIdx.x;
  const int wv = tid >> 6, lane = tid & 63;
  const int lrow = lane & 15, lkg = lane >> 4;
  const int n = blockIdx.x;
  const int j = n >> 3;
  const int bh = (n & 7) + 8 * (j >> 4);
  const int s0 = (j & 15) * 64;

  bf16x8 b0[4], b1[4];
#pragma unroll
  for (int ct = 0; ct < 4; ++ct) {
    const bf16* kp = kh + ((size_t)bh * SS + s0 + ct * 16 + lrow) * HD + lkg * 8;
    b0[ct] = *reinterpret_cast<const bf16x8*>(kp);
    b1[ct] = *reinterpret_cast<const bf16x8*>(kp + 32);
  }

  const f32x4 zero = {0.f, 0.f, 0.f, 0.f};
  float m[4] = {-1e30f, -1e30f, -1e30f, -1e30f};
  float d[4] = {0.f, 0.f, 0.f, 0.f};
  const bf16* qbase = qh + ((size_t)bh * LL + wv * 256 + lrow) * HD + lkg * 8;
  for (int i = 0; i < 16; ++i) {
    bf16x8 a0 = *reinterpret_cast<const bf16x8*>(qbase + (size_t)i * 16 * HD);
    bf16x8 a1 = *reinterpret_cast<const bf16x8*>(qbase + (size_t)i * 16 * HD + 32);
#pragma unroll
    for (int ct = 0; ct < 4; ++ct) {
      f32x4 c = zero;
      c = mfma16(a0, b0[ct], c);
      c = mfma16(a1, b1[ct], c);
      float tm = fmaxf(fmaxf(c[0], c[1]), fmaxf(c[2], c[3]));
      float nm = fmaxf(m[ct], tm);
      float dd = d[ct] * __expf(m[ct] - nm);
#pragma unroll
      for (int r = 0; r < 4; ++r) dd += __expf(c[r] - nm);
      d[ct] = dd; m[ct] = nm;
    }
  }
#pragma unroll
  for (int off = 16; off < 64; off <<= 1) {
#pragma unroll
    for (int ct = 0; ct < 4; ++ct) {
      float mo = __shfl_xor(m[ct], off);
      float dd = __shfl_xor(d[ct], off);
      float nm = fmaxf(m[ct], mo);
      d[ct] = d[ct] * __expf(m[ct] - nm) + dd * __expf(mo - nm);
      m[ct] = nm;
    }
  }
  if (lkg == 0) {
#pragma unroll
    for (int ct = 0; ct < 4; ++ct) { sm[wv][ct][lrow] = m[ct]; sd[wv][ct][lrow] = d[ct]; }
  }
  __syncthreads();
  if (wv == 0 && lkg == 0) {
#pragma unroll
    for (int ct = 0; ct < 4; ++ct) {
      float mm = sm[0][ct][lrow], dd = sd[0][ct][lrow];
#pragma unroll
      for (int w = 1; w < 4; ++w) {
        float mo = sm[w][ct][lrow], d2 = sd[w][ct][lrow];
        float nm = fmaxf(mm, mo);
        dd = dd * __expf(mm - nm) + d2 * __expf(mo - nm);
        mm = nm;
      }
      moff[(size_t)bh * SS + s0 + ct * 16 + lrow] = mm + __logf(dd);
    }
  }
}

// colsum_v[bh][d] = sum_s vhT[bh][d][s]
__global__ __launch_bounds__(64) void colsum_kernel(
    const bf16* __restrict__ vhT, float* __restrict__ colsum) {
  const int bh = blockIdx.x, d = blockIdx.y, lane = threadIdx.x;
  const bf16* p = vhT + ((size_t)bh * HD + d) * SS;
  float s = 0.f;
  for (int i = lane; i < SS; i += 64) s += (float)p[i];
#pragma unroll
  for (int off = 32; off; off >>= 1) s += __shfl_xor(s, off);
  if (lane == 0) colsum[bh * HD + d] = s;
}

// ---------------------------------------------------------------------------
// Attention v4: block = 8 waves x 16 q-rows (128 rows) of one bh, 512 threads.
// Same K/V LDS tiles as v3 (shared by 8 waves -> same density, 2x waves/CU).
// Staging: waves 0-3 stage K, waves 4-7 stage V. Row-sum via ones-MFMA.
// ---------------------------------------------------------------------------
__global__ __launch_bounds__(512) void attn_kernel(
    const bf16* __restrict__ qh, const bf16* __restrict__ kh,
    const bf16* __restrict__ vhT, const bf16* __restrict__ vmT,
    const bf16* __restrict__ k_mem, const float* __restrict__ gate_w,
    const float* __restrict__ moff, const float* __restrict__ colsum,
    bf16* __restrict__ attn2) {
  __shared__ bf16 Ks[2][2048];
  __shared__ bf16 Vs[2][2048];
  __shared__ bf16 wt[8][16][40];
  const int tid = threadIdx.x;
  const int wv = tid >> 6, lane = tid & 63;
  const int lrow = lane & 15, lkg = lane >> 4;
  const int bid = blockIdx.x;
  const int bh = (bid & 7) + 8 * (bid >> 6);
  const int b = bh >> 4, h = bh & 15;
  const int l0 = ((bid >> 3) & 7) * 128 + wv * 16;

  const bf16* qp = qh + ((size_t)bh * LL + l0 + lrow) * HD + lkg * 8;
  const bf16x8 aq0 = *reinterpret_cast<const bf16x8*>(qp);
  const bf16x8 aq1 = *reinterpret_cast<const bf16x8*>(qp + 32);

  bf16x8 ones;
#pragma unroll
  for (int i = 0; i < 8; ++i) ones[i] = (bf16)1.0f;

  const f32x4 zero = {0.f, 0.f, 0.f, 0.f};
  f32x4 acc[4], accm[4], racc = zero;
#pragma unroll
  for (int i = 0; i < 4; ++i) { acc[i] = zero; accm[i] = zero; }

  const int srow = lane & 31, sk8h = lane >> 5;  // staging decode
  const int wk = wv & 3;
  const bool isK = wv < 4;
  auto stageKV = [&](int buf, int s0) {
    if (isK)
      gload_lds16(kh + ((size_t)bh * SS + s0 + srow) * HD + (wk * 2 + sk8h) * 8,
                  &Ks[buf][wk * 512]);
    else
      gload_lds16(vhT + ((size_t)bh * HD + lane) * SS + s0 + wk * 8,
                  &Vs[buf][wk * 512]);
  };
  auto stageKVm = [&](int buf, int m0, bool needV) {
    if (isK)
      gload_lds16(k_mem + ((size_t)(m0 + srow) * BB + b) * EE + h * 64 + (wk * 2 + sk8h) * 8,
                  &Ks[buf][wk * 512]);
    else if (needV)
      gload_lds16(vmT + ((size_t)bh * HD + lane) * MM + m0 + wk * 8,
                  &Vs[buf][wk * 512]);
  };
  auto kfrag = [&](int buf, int t, int half) {
    return *reinterpret_cast<const bf16x8*>(&Ks[buf][((half * 4 + lkg) * 32 + t * 16 + lrow) * 8]);
  };
  auto vfrag = [&](int buf, int dt) {
    return *reinterpret_cast<const bf16x8*>(&Vs[buf][(lkg * 64 + dt * 16 + lrow) * 8]);
  };

  // ---- main attention ----
  stageKV(0, 0);
  __syncthreads();
  for (int s0 = 0; s0 < SS; s0 += 32) {
    const int buf = (s0 >> 5) & 1;
    if (s0 + 32 < SS) stageKV(buf ^ 1, s0 + 32);
    bf16x8 kf[2][2];
#pragma unroll
    for (int t = 0; t < 2; ++t) { kf[t][0] = kfrag(buf, t, 0); kf[t][1] = kfrag(buf, t, 1); }
    f32x4 sc[2];
#pragma unroll
    for (int t = 0; t < 2; ++t) {
      f32x4 c = zero;
      c = mfma16(aq0, kf[t][0], c);
      c = mfma16(aq1, kf[t][1], c);
      sc[t] = c;
    }
#pragma unroll
    for (int t = 0; t < 2; ++t) {
      const float mo = moff[(size_t)bh * SS + s0 + t * 16 + lrow];
#pragma unroll
      for (int r = 0; r < 4; ++r)
        wt[wv][lkg * 4 + r][t * 16 + lrow] = (bf16)__expf(sc[t][r] - mo);
    }
    const bf16x8 aw = *reinterpret_cast<const bf16x8*>(&wt[wv][lrow][lkg * 8]);
    racc = mfma16(aw, ones, racc);  // row sums of W, all cols identical
#pragma unroll
    for (int dt = 0; dt < 4; ++dt)
      acc[dt] = mfma16(aw, vfrag(buf, dt), acc[dt]);
    __syncthreads();
  }

  // ---- memory attention pass 1: per-row online stats ----
  float mx[4] = {-1e30f, -1e30f, -1e30f, -1e30f};
  float dn[4] = {0.f, 0.f, 0.f, 0.f};
  stageKVm(0, 0, false);
  __syncthreads();
  for (int m0 = 0; m0 < MM; m0 += 32) {
    const int buf = (m0 >> 5) & 1;
    if (m0 + 32 < MM) stageKVm(buf ^ 1, m0 + 32, false);
    bf16x8 kf[2][2];
#pragma unroll
    for (int t = 0; t < 2; ++t) { kf[t][0] = kfrag(buf, t, 0); kf[t][1] = kfrag(buf, t, 1); }
#pragma unroll
    for (int t = 0; t < 2; ++t) {
      f32x4 c = zero;
      c = mfma16(aq0, kf[t][0], c);
      c = mfma16(aq1, kf[t][1], c);
#pragma unroll
      for (int r = 0; r < 4; ++r) {
        float nm = fmaxf(mx[r], c[r]);
        dn[r] = dn[r] * __expf(mx[r] - nm) + __expf(c[r] - nm);
        mx[r] = nm;
      }
    }
    __syncthreads();
  }
#pragma unroll
  for (int off = 1; off < 16; off <<= 1) {
#pragma unroll
    for (int r = 0; r < 4; ++r) {
      float mo = __shfl_xor(mx[r], off);
      float dd = __shfl_xor(dn[r], off);
      float nm = fmaxf(mx[r], mo);
      dn[r] = dn[r] * __expf(mx[r] - nm) + dd * __expf(mo - nm);
      mx[r] = nm;
    }
  }
#pragma unroll
  for (int r = 0; r < 4; ++r) dn[r] = 1.f / dn[r];

  // ---- memory attention pass 2: weights + PV ----
  stageKVm(0, 0, true);
  __syncthreads();
  for (int m0 = 0; m0 < MM; m0 += 32) {
    const int buf = (m0 >> 5) & 1;
    if (m0 + 32 < MM) stageKVm(buf ^ 1, m0 + 32, true);
    bf16x8 kf[2][2];
#pragma unroll
    for (int t = 0; t < 2; ++t) { kf[t][0] = kfrag(buf, t, 0); kf[t][1] = kfrag(buf, t, 1); }
#pragma unroll
    for (int t = 0; t < 2; ++t) {
      f32x4 c = zero;
      c = mfma16(aq0, kf[t][0], c);
      c = mfma16(aq1, kf[t][1], c);
#pragma unroll
      for (int r = 0; r < 4; ++r)
        wt[wv][lkg * 4 + r][t * 16 + lrow] = (bf16)(__expf(c[r] - mx[r]) * dn[r]);
    }
    const bf16x8 aw = *reinterpret_cast<const bf16x8*>(&wt[wv][lrow][lkg * 8]);
#pragma unroll
    for (int dt = 0; dt < 4; ++dt)
      accm[dt] = mfma16(aw, vfrag(buf, dt), accm[dt]);
    __syncthreads();
  }

  // ---- epilogue: renormalize, gate, store ----
  float g = gate_w[h];
  g = 1.f / (1.f + __expf(-g));

#pragma unroll
  for (int dt = 0; dt < 4; ++dt) {
    const int d = dt * 16 + lrow;
    const float cv = colsum[bh * HD + d] * 1e-8f;
#pragma unroll
    for (int r = 0; r < 4; ++r) {
      const int lg = l0 + lkg * 4 + r;
      const float den = racc[r] + (float)SS * 1e-8f;
      const float amain = (acc[dt][r] + cv) / den;
      const float v = g * accm[dt][r] + (1.f - g) * amain;
      attn2[((size_t)lg * BB + b) * EE + h * 64 + d] = (bf16)v;
    }
  }
}

// ---------------------------------------------------------------------------
extern "C" void kernel_launch(void* const* d_in, const int* in_sizes, int n_in,
                              void* d_out, int out_size, void* d_ws, size_t ws_size,
                              hipStream_t stream) {
  const float* query = (const float*)d_in[0];
  const float* key_i = (const float*)d_in[1];
  const float* value = (const float*)d_in[2];
  const float* ipw   = (const float*)d_in[3];
  const float* ipb   = (const float*)d_in[4];
  const float* opw   = (const float*)d_in[5];
  const float* opb   = (const float*)d_in[6];
  const float* q_pe  = (const float*)d_in[7];
  const float* kv_pe = (const float*)d_in[8];
  const float* k_mem = (const float*)d_in[9];
  const float* v_mem = (const float*)d_in[10];
  const float* gate  = (const float*)d_in[11];

  char* ws = (char*)d_ws;
  bf16* qh    = (bf16*)(ws);                  // 8 MB  (BH, L, HD)
  bf16* kh    = (bf16*)(ws + (8u << 20));     // 8 MB  (BH, S, HD)
  bf16* vhT   = (bf16*)(ws + (16u << 20));    // 8 MB  (BH, HD, S)
  bf16* attn2 = (bf16*)(ws + (24u << 20));    // 8 MB  (L*B, E); xq scratch pre-attn
  bf16* vmT   = (bf16*)(ws + (32u << 20));    // 2 MB  (BH, HD, M)
  float* moff   = (float*)(ws + (34u << 20));                 // 256 KB
  float* colsum = (float*)(ws + (34u << 20) + (1u << 18));    // 16 KB
  bf16* wb    = (bf16*)(ws + (35u << 20));    // 6 MB  (3E, E) bf16
  bf16* opwb  = (bf16*)(ws + (41u << 20));    // 2 MB  (E, E)  bf16
  bf16* kmemb = (bf16*)(ws + (43u << 20));    // 2 MB  (M, B, E) bf16
  bf16* xq = attn2;
  bf16* xk = (bf16*)d_out;
  bf16* xv = (bf16*)d_out + (size_t)SS * BB * EE;

  dim3 blk(256);
  hipLaunchKernelGGL(cvt_all_kernel, dim3(8768), blk, 0, stream, ipw, opw, k_mem,
                     query, key_i, value, v_mem, wb, opwb, kmemb, xq, xk, xv, vmT);
  hipLaunchKernelGGL(gemm3_kernel, dim3(768), blk, 0, stream, xq, xk, xv, wb,
                     ipb, qh, kh, vhT);
  hipLaunchKernelGGL(rope_kernel, dim3(4096), blk, 0, stream, qh, kh, q_pe, kv_pe);
  hipLaunchKernelGGL(stats_kernel, dim3(1024), blk, 0, stream, qh, kh, moff);
  hipLaunchKernelGGL(colsum_kernel, dim3(64, 64), dim3(64), 0, stream, vhT, colsum);
  hipLaunchKernelGGL(attn_kernel, dim3(512), dim3(512), 0, stream, qh, kh, vhT, vmT,
                     kmemb, gate, moff, colsum, attn2);
  hipLaunchKernelGGL(gemm_out_kernel, dim3(512), blk, 0, stream, attn2, opwb, opb,
                     (float*)d_out);
}

// Round 11
// 249.312 us; speedup vs baseline: 1.0942x; 1.0942x over previous
//
#include <hip/hip_runtime.h>
#include <hip/hip_bf16.h>

typedef __bf16 bf16;
typedef __bf16 bf16x8 __attribute__((ext_vector_type(8)));
typedef float f32x4 __attribute__((ext_vector_type(4)));

#define LL 1024
#define SS 1024
#define BB 4
#define EE 1024
#define HH 16
#define MM 256
#define HD 64
#define BH 64

__device__ __forceinline__ f32x4 mfma16(bf16x8 a, bf16x8 b, f32x4 c) {
  return __builtin_amdgcn_mfma_f32_16x16x32_bf16(a, b, c, 0, 0, 0);
}

__device__ __forceinline__ void gload_lds16(const bf16* g, bf16* l) {
  __builtin_amdgcn_global_load_lds(
      (const __attribute__((address_space(1))) unsigned int*)(g),
      (__attribute__((address_space(3))) unsigned int*)(l), 16, 0, 0);
}

// load 8 contiguous f32 (32B-aligned) -> bf16x8 fragment
__device__ __forceinline__ bf16x8 cvt8(const float* p) {
  const f32x4 lo = *reinterpret_cast<const f32x4*>(p);
  const f32x4 hi = *reinterpret_cast<const f32x4*>(p + 4);
  bf16x8 r;
  r[0] = (bf16)lo[0]; r[1] = (bf16)lo[1]; r[2] = (bf16)lo[2]; r[3] = (bf16)lo[3];
  r[4] = (bf16)hi[0]; r[5] = (bf16)hi[1]; r[6] = (bf16)hi[2]; r[7] = (bf16)hi[3];
  return r;
}

// fused f32->bf16 conversion over six regions + vmT transpose (bid >= 8704).
// xv is stored B-MAJOR: xv[b][s][E]  (for the transposed V GEMM).
__global__ __launch_bounds__(256) void cvt_all_kernel(
    const float* __restrict__ ipw, const float* __restrict__ opw,
    const float* __restrict__ k_mem, const float* __restrict__ query,
    const float* __restrict__ key_i, const float* __restrict__ value,
    const float* __restrict__ v_mem,
    bf16* __restrict__ wb, bf16* __restrict__ opwb, bf16* __restrict__ kmemb,
    bf16* __restrict__ xq, bf16* __restrict__ xk, bf16* __restrict__ xv,
    bf16* __restrict__ vmT) {
  const int bid = blockIdx.x, tid = threadIdx.x;
  if (bid >= 8704) {  // vmT[bh][d][m] = v_mem[m][b][h*64+d]
    const int bh = bid - 8704;
    const int b = bh >> 4, h = bh & 15;
    const int d = tid & 63;
    const int mo = tid >> 6;
    for (int m = mo; m < MM; m += 4) {
      float v = v_mem[((size_t)m * BB + b) * EE + h * 64 + d];
      vmT[((size_t)bh * HD + d) * MM + m] = (bf16)v;
    }
    return;
  }
  if (bid >= 6656) {  // value -> xv b-major
    const size_t i8 = ((size_t)(bid - 6656) * 256 + tid) * 8;
    const int e = (int)(i8 & (EE - 1));
    const int row = (int)(i8 >> 10);      // s*4 + b
    const int s = row >> 2, b = row & 3;
    *reinterpret_cast<bf16x8*>(xv + (((size_t)b * SS + s) << 10) + e) = cvt8(value + i8);
    return;
  }
  const float* src; bf16* dst; int base;
  if (bid < 1536)      { src = ipw;   dst = wb;    base = 0; }
  else if (bid < 2048) { src = opw;   dst = opwb;  base = 1536; }
  else if (bid < 2560) { src = k_mem; dst = kmemb; base = 2048; }
  else if (bid < 4608) { src = query; dst = xq;    base = 2560; }
  else                 { src = key_i; dst = xk;    base = 4608; }
  const size_t i = ((size_t)(bid - base) * 256 + tid) * 8;
  *reinterpret_cast<bf16x8*>(dst + i) = cvt8(src + i);
}

// ---------------------------------------------------------------------------
// In-place interleaved rotary on qh and kh (pure HBM-bound elementwise).
// ---------------------------------------------------------------------------
__global__ __launch_bounds__(256) void rope_kernel(
    bf16* __restrict__ qh, bf16* __restrict__ kh,
    const float* __restrict__ q_pe, const float* __restrict__ kv_pe) {
  const size_t CP = (size_t)BH * LL * HD / 8;  // 524288 chunks per tensor
  size_t gi = (size_t)blockIdx.x * 256 + threadIdx.x;
  bf16* x; const float* pe;
  if (gi < CP) { x = qh; pe = q_pe; }
  else         { x = kh; pe = kv_pe; gi -= CP; }
  const int d8 = gi & 7;
  const int t  = (int)((gi >> 3) & (LL - 1));
  const int bh = (int)(gi >> 13);
  const int b = bh >> 4, h = bh & 15;
  bf16* xp = x + gi * 8;
  const float* pp = pe + (((size_t)b * LL + t) * EE + h * 64 + d8 * 8) * 2;
  bf16x8 v = *reinterpret_cast<const bf16x8*>(xp);
  const f32x4 p0 = *reinterpret_cast<const f32x4*>(pp);
  const f32x4 p1 = *reinterpret_cast<const f32x4*>(pp + 4);
  const f32x4 p2 = *reinterpret_cast<const f32x4*>(pp + 8);
  const f32x4 p3 = *reinterpret_cast<const f32x4*>(pp + 12);
  float cs[8], sn[8], xv[8];
  cs[0]=p0[0]; sn[0]=p0[1]; cs[1]=p0[2]; sn[1]=p0[3];
  cs[2]=p1[0]; sn[2]=p1[1]; cs[3]=p1[2]; sn[3]=p1[3];
  cs[4]=p2[0]; sn[4]=p2[1]; cs[5]=p2[2]; sn[5]=p2[3];
  cs[6]=p3[0]; sn[6]=p3[1]; cs[7]=p3[2]; sn[7]=p3[3];
#pragma unroll
  for (int j = 0; j < 8; ++j) xv[j] = (float)v[j];
  bf16x8 o;
#pragma unroll
  for (int j = 0; j < 8; j += 2) {
    o[j]     = (bf16)(xv[j]     * cs[j]     - xv[j + 1] * sn[j]);
    o[j + 1] = (bf16)(xv[j + 1] * cs[j + 1] + xv[j]     * sn[j + 1]);
  }
  *reinterpret_cast<bf16x8*>(xp) = o;
}

// ---------------------------------------------------------------------------
// Fused q/k/v projection GEMM: BM=BN=128, 768 blocks, 4 waves 2x2, dbuf LDS.
// which 0/1: out[rowg=t*4+b][col=e_out] = X W^T  -> qh/kh[bh][t][d]
// which 2  : TRANSPOSED product V^T = W_v X_v^T (A=W_v rows=e_out,
//            B=xv b-major rows=b*SS+s) -> vhT[bh][d][s], s-coalesced writes.
// ---------------------------------------------------------------------------
__global__ __launch_bounds__(256) void gemm3_kernel(
    const bf16* __restrict__ xq, const bf16* __restrict__ xk,
    const bf16* __restrict__ xv, const bf16* __restrict__ wb,
    const float* __restrict__ ipb, bf16* __restrict__ qh,
    bf16* __restrict__ kh, bf16* __restrict__ vhT) {
  __shared__ bf16 As[2][4096];
  __shared__ bf16 Bs[2][4096];
  const int tid = threadIdx.x;
  const int wv = tid >> 6, lane = tid & 63;
  const int lrow = lane & 15, lkg = lane >> 4;
  const int wr = wv >> 1, wc = wv & 1;
  const int n = (blockIdx.x & 7) * 96 + (blockIdx.x >> 3);  // XCD-chunked
  const int which = n >> 8, sub = n & 255;

  const bf16* X; const bf16* W;
  int rowA0, colB0;
  if (which == 2) {
    X = wb + 2 * (size_t)EE * EE;       // W_v (1024 x 1024)
    W = xv;                              // xv b-major (4096 x 1024)
    rowA0 = (sub & 7) * 128;             // e_out tile (8 tiles)
    colB0 = (sub >> 3) * 128;            // b*SS+s tile (32 tiles)
  } else {
    X = (which == 0) ? xq : xk;
    W = wb + (size_t)which * EE * EE;
    rowA0 = (sub >> 3) * 128;
    colB0 = (sub & 7) * 128;
  }

  const f32x4 zero = {0.f, 0.f, 0.f, 0.f};
  f32x4 acc[4][4];
#pragma unroll
  for (int i = 0; i < 4; ++i)
#pragma unroll
    for (int j = 0; j < 4; ++j) acc[i][j] = zero;

  auto stage = [&](int buf, int k0) {
#pragma unroll
    for (int t = 0; t < 2; ++t) {
      const int i = wv * 2 + t;
      const int slot = i * 64 + lane;
      const int srow = slot & 127, sk8 = slot >> 7;
      gload_lds16(X + (size_t)(rowA0 + srow) * EE + k0 + sk8 * 8, &As[buf][i * 512]);
      gload_lds16(W + (size_t)(colB0 + srow) * EE + k0 + sk8 * 8, &Bs[buf][i * 512]);
    }
  };

  stage(0, 0);
  __syncthreads();
  for (int ks = 0; ks < 32; ++ks) {
    const int buf = ks & 1;
    if (ks < 31) stage(buf ^ 1, (ks + 1) * 32);
    bf16x8 av[4], bv[4];
#pragma unroll
    for (int i = 0; i < 4; ++i) {
      av[i] = *reinterpret_cast<const bf16x8*>(&As[buf][lkg * 1024 + (wr * 64 + i * 16 + lrow) * 8]);
      bv[i] = *reinterpret_cast<const bf16x8*>(&Bs[buf][lkg * 1024 + (wc * 64 + i * 16 + lrow) * 8]);
    }
#pragma unroll
    for (int mt = 0; mt < 4; ++mt)
#pragma unroll
      for (int nt = 0; nt < 4; ++nt)
        acc[mt][nt] = mfma16(av[mt], bv[nt], acc[mt][nt]);
    __syncthreads();
  }

  if (which == 2) {
    // rows = e_out (h*64+d), cols = b*SS+s; bias indexed by ROW.
#pragma unroll
    for (int mt = 0; mt < 4; ++mt) {
#pragma unroll
      for (int r = 0; r < 4; ++r) {
        const int rowg = rowA0 + wr * 64 + mt * 16 + lkg * 4 + r;
        const float bs = ipb[2 * EE + rowg];
        const int h = rowg >> 6, d = rowg & 63;
#pragma unroll
        for (int nt = 0; nt < 4; ++nt) {
          const int c = colB0 + wc * 64 + nt * 16 + lrow;
          const int b = c >> 10, s = c & (SS - 1);
          vhT[(((size_t)(b * HH + h)) * HD + d) * SS + s] = (bf16)(acc[mt][nt][r] + bs);
        }
      }
    }
  } else {
#pragma unroll
    for (int nt = 0; nt < 4; ++nt) {
      const int col = colB0 + wc * 64 + nt * 16 + lrow;
      const float bs = ipb[which * EE + col];
      const int h = col >> 6, d = col & 63;
#pragma unroll
      for (int mt = 0; mt < 4; ++mt) {
#pragma unroll
        for (int r = 0; r < 4; ++r) {
          const int rowg = rowA0 + wr * 64 + mt * 16 + lkg * 4 + r;
          const int t = rowg >> 2;
          const int b = rowg & 3;
          float v = acc[mt][nt][r] + bs;
          if (which == 0) v *= 0.125f;
          const int bh = b * HH + h;
          if (which == 1)
            kh[((size_t)bh * LL + t) * HD + d] = (bf16)v;
          else
            qh[((size_t)bh * LL + t) * HD + d] = (bf16)v;
        }
      }
    }
  }
}

// ---------------------------------------------------------------------------
// Out-projection GEMM: BM=128, BN=64 -> 512 blocks. Writes f32 d_out.
// ---------------------------------------------------------------------------
__global__ __launch_bounds__(256) void gemm_out_kernel(
    const bf16* __restrict__ Xb, const bf16* __restrict__ W,
    const float* __restrict__ bias, float* __restrict__ outf) {
  __shared__ bf16 As[2][4096];
  __shared__ bf16 Bs[2][2048];
  const int tid = threadIdx.x;
  const int wv = tid >> 6, lane = tid & 63;
  const int lrow = lane & 15, lkg = lane >> 4;
  const int wr = wv >> 1, wc = wv & 1;
  const int n = (blockIdx.x & 7) * 64 + (blockIdx.x >> 3);
  const int rowt = n >> 4, colt = n & 15;
  const int rowA0 = rowt * 128, colB0 = colt * 64;

  const f32x4 zero = {0.f, 0.f, 0.f, 0.f};
  f32x4 acc[4][2];
#pragma unroll
  for (int i = 0; i < 4; ++i)
#pragma unroll
    for (int j = 0; j < 2; ++j) acc[i][j] = zero;

  auto stage = [&](int buf, int k0) {
#pragma unroll
    for (int t = 0; t < 2; ++t) {
      const int i = wv * 2 + t;
      const int slot = i * 64 + lane;
      const int srow = slot & 127, sk8 = slot >> 7;
      gload_lds16(Xb + (size_t)(rowA0 + srow) * EE + k0 + sk8 * 8, &As[buf][i * 512]);
    }
    {
      const int slot = wv * 64 + lane;
      const int srow = slot & 63, sk8 = slot >> 6;
      gload_lds16(W + (size_t)(colB0 + srow) * EE + k0 + sk8 * 8, &Bs[buf][wv * 512]);
    }
  };

  stage(0, 0);
  __syncthreads();
  for (int ks = 0; ks < 32; ++ks) {
    const int buf = ks & 1;
    if (ks < 31) stage(buf ^ 1, (ks + 1) * 32);
    bf16x8 av[4], bv[2];
#pragma unroll
    for (int i = 0; i < 4; ++i)
      av[i] = *reinterpret_cast<const bf16x8*>(&As[buf][lkg * 1024 + (wr * 64 + i * 16 + lrow) * 8]);
#pragma unroll
    for (int j = 0; j < 2; ++j)
      bv[j] = *reinterpret_cast<const bf16x8*>(&Bs[buf][lkg * 512 + (wc * 32 + j * 16 + lrow) * 8]);
#pragma unroll
    for (int mt = 0; mt < 4; ++mt)
#pragma unroll
      for (int nt = 0; nt < 2; ++nt)
        acc[mt][nt] = mfma16(av[mt], bv[nt], acc[mt][nt]);
    __syncthreads();
  }

#pragma unroll
  for (int nt = 0; nt < 2; ++nt) {
    const int col = colB0 + wc * 32 + nt * 16 + lrow;
    const float bs = bias[col];
#pragma unroll
    for (int mt = 0; mt < 4; ++mt)
#pragma unroll
      for (int r = 0; r < 4; ++r) {
        const int rowg = rowA0 + wr * 64 + mt * 16 + lkg * 4 + r;
        outf[(size_t)rowg * EE + col] = acc[mt][nt][r] + bs;
      }
  }
}

// ---------------------------------------------------------------------------
// Column softmax stats over L for each (bh, s): moff = m + ln(sum exp(sc-m)).
// ---------------------------------------------------------------------------
__global__ __launch_bounds__(256) void stats_kernel(
    const bf16* __restrict__ qh, const bf16* __restrict__ kh,
    float* __restrict__ moff) {
  __shared__ float sm[4][4][16], sd[4][4][16];
  const int tid = threadIdx.x;
  const int wv = tid >> 6, lane = tid & 63;
  const int lrow = lane & 15, lkg = lane >> 4;
  const int n = blockIdx.x;
  const int j = n >> 3;
  const int bh = (n & 7) + 8 * (j >> 4);
  const int s0 = (j & 15) * 64;

  bf16x8 b0[4], b1[4];
#pragma unroll
  for (int ct = 0; ct < 4; ++ct) {
    const bf16* kp = kh + ((size_t)bh * SS + s0 + ct * 16 + lrow) * HD + lkg * 8;
    b0[ct] = *reinterpret_cast<const bf16x8*>(kp);
    b1[ct] = *reinterpret_cast<const bf16x8*>(kp + 32);
  }

  const f32x4 zero = {0.f, 0.f, 0.f, 0.f};
  float m[4] = {-1e30f, -1e30f, -1e30f, -1e30f};
  float d[4] = {0.f, 0.f, 0.f, 0.f};
  const bf16* qbase = qh + ((size_t)bh * LL + wv * 256 + lrow) * HD + lkg * 8;
  for (int i = 0; i < 16; ++i) {
    bf16x8 a0 = *reinterpret_cast<const bf16x8*>(qbase + (size_t)i * 16 * HD);
    bf16x8 a1 = *reinterpret_cast<const bf16x8*>(qbase + (size_t)i * 16 * HD + 32);
#pragma unroll
    for (int ct = 0; ct < 4; ++ct) {
      f32x4 c = zero;
      c = mfma16(a0, b0[ct], c);
      c = mfma16(a1, b1[ct], c);
      float tm = fmaxf(fmaxf(c[0], c[1]), fmaxf(c[2], c[3]));
      float nm = fmaxf(m[ct], tm);
      float dd = d[ct] * __expf(m[ct] - nm);
#pragma unroll
      for (int r = 0; r < 4; ++r) dd += __expf(c[r] - nm);
      d[ct] = dd; m[ct] = nm;
    }
  }
#pragma unroll
  for (int off = 16; off < 64; off <<= 1) {
#pragma unroll
    for (int ct = 0; ct < 4; ++ct) {
      float mo = __shfl_xor(m[ct], off);
      float dd = __shfl_xor(d[ct], off);
      float nm = fmaxf(m[ct], mo);
      d[ct] = d[ct] * __expf(m[ct] - nm) + dd * __expf(mo - nm);
      m[ct] = nm;
    }
  }
  if (lkg == 0) {
#pragma unroll
    for (int ct = 0; ct < 4; ++ct) { sm[wv][ct][lrow] = m[ct]; sd[wv][ct][lrow] = d[ct]; }
  }
  __syncthreads();
  if (wv == 0 && lkg == 0) {
#pragma unroll
    for (int ct = 0; ct < 4; ++ct) {
      float mm = sm[0][ct][lrow], dd = sd[0][ct][lrow];
#pragma unroll
      for (int w = 1; w < 4; ++w) {
        float mo = sm[w][ct][lrow], d2 = sd[w][ct][lrow];
        float nm = fmaxf(mm, mo);
        dd = dd * __expf(mm - nm) + d2 * __expf(mo - nm);
        mm = nm;
      }
      moff[(size_t)bh * SS + s0 + ct * 16 + lrow] = mm + __logf(dd);
    }
  }
}

// colsum_v[bh][d] = sum_s vhT[bh][d][s]
__global__ __launch_bounds__(64) void colsum_kernel(
    const bf16* __restrict__ vhT, float* __restrict__ colsum) {
  const int bh = blockIdx.x, d = blockIdx.y, lane = threadIdx.x;
  const bf16* p = vhT + ((size_t)bh * HD + d) * SS;
  float s = 0.f;
  for (int i = lane; i < SS; i += 64) s += (float)p[i];
#pragma unroll
  for (int off = 32; off; off >>= 1) s += __shfl_xor(s, off);
  if (lane == 0) colsum[bh * HD + d] = s;
}

// ---------------------------------------------------------------------------
// Attention v3 (proven best): block = 4 waves x 32 q-rows (128 rows) of one
// bh. K/V tiles staged in LDS (global_load_lds), shared by 4 waves, dbuf.
// Row-sum via ones-MFMA. XCD-grouped.
// ---------------------------------------------------------------------------
__global__ __launch_bounds__(256) void attn_kernel(
    const bf16* __restrict__ qh, const bf16* __restrict__ kh,
    const bf16* __restrict__ vhT, const bf16* __restrict__ vmT,
    const bf16* __restrict__ k_mem, const float* __restrict__ gate_w,
    const float* __restrict__ moff, const float* __restrict__ colsum,
    bf16* __restrict__ attn2) {
  __shared__ bf16 Ks[2][2048];
  __shared__ bf16 Vs[2][2048];
  __shared__ bf16 wt[4][32][40];
  const int tid = threadIdx.x;
  const int wv = tid >> 6, lane = tid & 63;
  const int lrow = lane & 15, lkg = lane >> 4;
  const int bid = blockIdx.x;
  const int bh = (bid & 7) + 8 * (bid >> 6);
  const int b = bh >> 4, h = bh & 15;
  const int l0 = ((bid >> 3) & 7) * 128 + wv * 32;

  bf16x8 aq[2][2];
#pragma unroll
  for (int rt = 0; rt < 2; ++rt) {
    const bf16* qp = qh + ((size_t)bh * LL + l0 + rt * 16 + lrow) * HD + lkg * 8;
    aq[rt][0] = *reinterpret_cast<const bf16x8*>(qp);
    aq[rt][1] = *reinterpret_cast<const bf16x8*>(qp + 32);
  }

  bf16x8 ones;
#pragma unroll
  for (int i = 0; i < 8; ++i) ones[i] = (bf16)1.0f;

  const f32x4 zero = {0.f, 0.f, 0.f, 0.f};
  f32x4 acc[2][4], accm[2][4], racc[2];
#pragma unroll
  for (int rt = 0; rt < 2; ++rt) {
    racc[rt] = zero;
#pragma unroll
    for (int i = 0; i < 4; ++i) { acc[rt][i] = zero; accm[rt][i] = zero; }
  }

  const int srow = lane & 31, sk8h = lane >> 5;  // staging decode
  auto stageK = [&](int buf, int s0) {
    gload_lds16(kh + ((size_t)bh * SS + s0 + srow) * HD + (wv * 2 + sk8h) * 8,
                &Ks[buf][wv * 512]);
  };
  auto stageV = [&](int buf, int s0) {
    gload_lds16(vhT + ((size_t)bh * HD + lane) * SS + s0 + wv * 8,
                &Vs[buf][wv * 512]);
  };
  auto stageKM = [&](int buf, int m0) {
    gload_lds16(k_mem + ((size_t)(m0 + srow) * BB + b) * EE + h * 64 + (wv * 2 + sk8h) * 8,
                &Ks[buf][wv * 512]);
  };
  auto stageVM = [&](int buf, int m0) {
    gload_lds16(vmT + ((size_t)bh * HD + lane) * MM + m0 + wv * 8,
                &Vs[buf][wv * 512]);
  };
  auto kfrag = [&](int buf, int t, int half) {
    return *reinterpret_cast<const bf16x8*>(&Ks[buf][((half * 4 + lkg) * 32 + t * 16 + lrow) * 8]);
  };
  auto vfrag = [&](int buf, int dt) {
    return *reinterpret_cast<const bf16x8*>(&Vs[buf][(lkg * 64 + dt * 16 + lrow) * 8]);
  };

  // ---- main attention ----
  stageK(0, 0); stageV(0, 0);
  __syncthreads();
  for (int s0 = 0; s0 < SS; s0 += 32) {
    const int buf = (s0 >> 5) & 1;
    if (s0 + 32 < SS) { stageK(buf ^ 1, s0 + 32); stageV(buf ^ 1, s0 + 32); }
    bf16x8 kf[2][2];
#pragma unroll
    for (int t = 0; t < 2; ++t) { kf[t][0] = kfrag(buf, t, 0); kf[t][1] = kfrag(buf, t, 1); }
    f32x4 sc[2][2];
#pragma unroll
    for (int rt = 0; rt < 2; ++rt)
#pragma unroll
      for (int t = 0; t < 2; ++t) {
        f32x4 c = zero;
        c = mfma16(aq[rt][0], kf[t][0], c);
        c = mfma16(aq[rt][1], kf[t][1], c);
        sc[rt][t] = c;
      }
#pragma unroll
    for (int t = 0; t < 2; ++t) {
      const float mo = moff[(size_t)bh * SS + s0 + t * 16 + lrow];
#pragma unroll
      for (int rt = 0; rt < 2; ++rt)
#pragma unroll
        for (int r = 0; r < 4; ++r)
          wt[wv][rt * 16 + lkg * 4 + r][t * 16 + lrow] = (bf16)__expf(sc[rt][t][r] - mo);
    }
    bf16x8 aw[2];
#pragma unroll
    for (int rt = 0; rt < 2; ++rt) {
      aw[rt] = *reinterpret_cast<const bf16x8*>(&wt[wv][rt * 16 + lrow][lkg * 8]);
      racc[rt] = mfma16(aw[rt], ones, racc[rt]);
    }
#pragma unroll
    for (int dt = 0; dt < 4; ++dt) {
      bf16x8 bv = vfrag(buf, dt);
#pragma unroll
      for (int rt = 0; rt < 2; ++rt) acc[rt][dt] = mfma16(aw[rt], bv, acc[rt][dt]);
    }
    __syncthreads();
  }

  // ---- memory attention pass 1: per-row online stats ----
  float mx[2][4], dn[2][4];
#pragma unroll
  for (int rt = 0; rt < 2; ++rt)
#pragma unroll
    for (int r = 0; r < 4; ++r) { mx[rt][r] = -1e30f; dn[rt][r] = 0.f; }
  stageKM(0, 0);
  __syncthreads();
  for (int m0 = 0; m0 < MM; m0 += 32) {
    const int buf = (m0 >> 5) & 1;
    if (m0 + 32 < MM) stageKM(buf ^ 1, m0 + 32);
    bf16x8 kf[2][2];
#pragma unroll
    for (int t = 0; t < 2; ++t) { kf[t][0] = kfrag(buf, t, 0); kf[t][1] = kfrag(buf, t, 1); }
#pragma unroll
    for (int rt = 0; rt < 2; ++rt)
#pragma unroll
      for (int t = 0; t < 2; ++t) {
        f32x4 c = zero;
        c = mfma16(aq[rt][0], kf[t][0], c);
        c = mfma16(aq[rt][1], kf[t][1], c);
#pragma unroll
        for (int r = 0; r < 4; ++r) {
          float nm = fmaxf(mx[rt][r], c[r]);
          dn[rt][r] = dn[rt][r] * __expf(mx[rt][r] - nm) + __expf(c[r] - nm);
          mx[rt][r] = nm;
        }
      }
    __syncthreads();
  }
#pragma unroll
  for (int off = 1; off < 16; off <<= 1) {
#pragma unroll
    for (int rt = 0; rt < 2; ++rt)
#pragma unroll
      for (int r = 0; r < 4; ++r) {
        float mo = __shfl_xor(mx[rt][r], off);
        float dd = __shfl_xor(dn[rt][r], off);
        float nm = fmaxf(mx[rt][r], mo);
        dn[rt][r] = dn[rt][r] * __expf(mx[rt][r] - nm) + dd * __expf(mo - nm);
        mx[rt][r] = nm;
      }
  }
#pragma unroll
  for (int rt = 0; rt < 2; ++rt)
#pragma unroll
    for (int r = 0; r < 4; ++r) dn[rt][r] = 1.f / dn[rt][r];

  // ---- memory attention pass 2: weights + PV ----
  stageKM(0, 0); stageVM(0, 0);
  __syncthreads();
  for (int m0 = 0; m0 < MM; m0 += 32) {
    const int buf = (m0 >> 5) & 1;
    if (m0 + 32 < MM) { stageKM(buf ^ 1, m0 + 32); stageVM(buf ^ 1, m0 + 32); }
    bf16x8 kf[2][2];
#pragma unroll
    for (int t = 0; t < 2; ++t) { kf[t][0] = kfrag(buf, t, 0); kf[t][1] = kfrag(buf, t, 1); }
#pragma unroll
    for (int rt = 0; rt < 2; ++rt)
#pragma unroll
      for (int t = 0; t < 2; ++t) {
        f32x4 c = zero;
        c = mfma16(aq[rt][0], kf[t][0], c);
        c = mfma16(aq[rt][1], kf[t][1], c);
#pragma unroll
        for (int r = 0; r < 4; ++r)
          wt[wv][rt * 16 + lkg * 4 + r][t * 16 + lrow] = (bf16)(__expf(c[r] - mx[rt][r]) * dn[rt][r]);
      }
    bf16x8 aw[2];
#pragma unroll
    for (int rt = 0; rt < 2; ++rt)
      aw[rt] = *reinterpret_cast<const bf16x8*>(&wt[wv][rt * 16 + lrow][lkg * 8]);
#pragma unroll
    for (int dt = 0; dt < 4; ++dt) {
      bf16x8 bv = vfrag(buf, dt);
#pragma unroll
      for (int rt = 0; rt < 2; ++rt) accm[rt][dt] = mfma16(aw[rt], bv, accm[rt][dt]);
    }
    __syncthreads();
  }

  // ---- epilogue: renormalize, gate, store ----
  float g = gate_w[h];
  g = 1.f / (1.f + __expf(-g));

#pragma unroll
  for (int dt = 0; dt < 4; ++dt) {
    const int d = dt * 16 + lrow;
    const float cv = colsum[bh * HD + d] * 1e-8f;
#pragma unroll
    for (int rt = 0; rt < 2; ++rt)
#pragma unroll
      for (int r = 0; r < 4; ++r) {
        const int lg = l0 + rt * 16 + lkg * 4 + r;
        const float den = racc[rt][r] + (float)SS * 1e-8f;
        const float amain = (acc[rt][dt][r] + cv) / den;
        const float v = g * accm[rt][dt][r] + (1.f - g) * amain;
        attn2[((size_t)lg * BB + b) * EE + h * 64 + d] = (bf16)v;
      }
  }
}

// ---------------------------------------------------------------------------
extern "C" void kernel_launch(void* const* d_in, const int* in_sizes, int n_in,
                              void* d_out, int out_size, void* d_ws, size_t ws_size,
                              hipStream_t stream) {
  const float* query = (const float*)d_in[0];
  const float* key_i = (const float*)d_in[1];
  const float* value = (const float*)d_in[2];
  const float* ipw   = (const float*)d_in[3];
  const float* ipb   = (const float*)d_in[4];
  const float* opw   = (const float*)d_in[5];
  const float* opb   = (const float*)d_in[6];
  const float* q_pe  = (const float*)d_in[7];
  const float* kv_pe = (const float*)d_in[8];
  const float* k_mem = (const float*)d_in[9];
  const float* v_mem = (const float*)d_in[10];
  const float* gate  = (const float*)d_in[11];

  char* ws = (char*)d_ws;
  bf16* qh    = (bf16*)(ws);                  // 8 MB  (BH, L, HD)
  bf16* kh    = (bf16*)(ws + (8u << 20));     // 8 MB  (BH, S, HD)
  bf16* vhT   = (bf16*)(ws + (16u << 20));    // 8 MB  (BH, HD, S)
  bf16* attn2 = (bf16*)(ws + (24u << 20));    // 8 MB  (L*B, E); xq scratch pre-attn
  bf16* vmT   = (bf16*)(ws + (32u << 20));    // 2 MB  (BH, HD, M)
  float* moff   = (float*)(ws + (34u << 20));                 // 256 KB
  float* colsum = (float*)(ws + (34u << 20) + (1u << 18));    // 16 KB
  bf16* wb    = (bf16*)(ws + (35u << 20));    // 6 MB  (3E, E) bf16
  bf16* opwb  = (bf16*)(ws + (41u << 20));    // 2 MB  (E, E)  bf16
  bf16* kmemb = (bf16*)(ws + (43u << 20));    // 2 MB  (M, B, E) bf16
  bf16* xq = attn2;
  bf16* xk = (bf16*)d_out;
  bf16* xv = (bf16*)d_out + (size_t)SS * BB * EE;  // b-major (B, S, E)

  dim3 blk(256);
  hipLaunchKernelGGL(cvt_all_kernel, dim3(8768), blk, 0, stream, ipw, opw, k_mem,
                     query, key_i, value, v_mem, wb, opwb, kmemb, xq, xk, xv, vmT);
  hipLaunchKernelGGL(gemm3_kernel, dim3(768), blk, 0, stream, xq, xk, xv, wb,
                     ipb, qh, kh, vhT);
  hipLaunchKernelGGL(rope_kernel, dim3(4096), blk, 0, stream, qh, kh, q_pe, kv_pe);
  hipLaunchKernelGGL(stats_kernel, dim3(1024), blk, 0, stream, qh, kh, moff);
  hipLaunchKernelGGL(colsum_kernel, dim3(64, 64), dim3(64), 0, stream, vhT, colsum);
  hipLaunchKernelGGL(attn_kernel, dim3(512), blk, 0, stream, qh, kh, vhT, vmT,
                     kmemb, gate, moff, colsum, attn2);
  hipLaunchKernelGGL(gemm_out_kernel, dim3(512), blk, 0, stream, attn2, opwb, opb,
                     (float*)d_out);
}

// Round 12
// 226.859 us; speedup vs baseline: 1.2025x; 1.0990x over previous
//
#include <hip/hip_runtime.h>
#include <hip/hip_bf16.h>

typedef __bf16 bf16;
typedef __bf16 bf16x8 __attribute__((ext_vector_type(8)));
typedef float f32x4 __attribute__((ext_vector_type(4)));

#define LL 1024
#define SS 1024
#define BB 4
#define EE 1024
#define HH 16
#define MM 256
#define HD 64
#define BH 64

__device__ __forceinline__ f32x4 mfma16(bf16x8 a, bf16x8 b, f32x4 c) {
  return __builtin_amdgcn_mfma_f32_16x16x32_bf16(a, b, c, 0, 0, 0);
}

__device__ __forceinline__ void gload_lds16(const bf16* g, bf16* l) {
  __builtin_amdgcn_global_load_lds(
      (const __attribute__((address_space(1))) unsigned int*)(g),
      (__attribute__((address_space(3))) unsigned int*)(l), 16, 0, 0);
}

// load 8 contiguous f32 (32B-aligned) -> bf16x8 fragment
__device__ __forceinline__ bf16x8 cvt8(const float* p) {
  const f32x4 lo = *reinterpret_cast<const f32x4*>(p);
  const f32x4 hi = *reinterpret_cast<const f32x4*>(p + 4);
  bf16x8 r;
  r[0] = (bf16)lo[0]; r[1] = (bf16)lo[1]; r[2] = (bf16)lo[2]; r[3] = (bf16)lo[3];
  r[4] = (bf16)hi[0]; r[5] = (bf16)hi[1]; r[6] = (bf16)hi[2]; r[7] = (bf16)hi[3];
  return r;
}

// fused f32->bf16 conversion over six regions (pure streaming, no stragglers).
// xv is stored B-MAJOR: xv[b][s][E]  (for the transposed V GEMM).
__global__ __launch_bounds__(256) void cvt_all_kernel(
    const float* __restrict__ ipw, const float* __restrict__ opw,
    const float* __restrict__ k_mem, const float* __restrict__ query,
    const float* __restrict__ key_i, const float* __restrict__ value,
    bf16* __restrict__ wb, bf16* __restrict__ opwb, bf16* __restrict__ kmemb,
    bf16* __restrict__ xq, bf16* __restrict__ xk, bf16* __restrict__ xv) {
  const int bid = blockIdx.x, tid = threadIdx.x;
  if (bid >= 6656) {  // value -> xv b-major
    const size_t i8 = ((size_t)(bid - 6656) * 256 + tid) * 8;
    const int e = (int)(i8 & (EE - 1));
    const int row = (int)(i8 >> 10);      // s*4 + b
    const int s = row >> 2, b = row & 3;
    *reinterpret_cast<bf16x8*>(xv + (((size_t)b * SS + s) << 10) + e) = cvt8(value + i8);
    return;
  }
  const float* src; bf16* dst; int base;
  if (bid < 1536)      { src = ipw;   dst = wb;    base = 0; }
  else if (bid < 2048) { src = opw;   dst = opwb;  base = 1536; }
  else if (bid < 2560) { src = k_mem; dst = kmemb; base = 2048; }
  else if (bid < 4608) { src = query; dst = xq;    base = 2560; }
  else                 { src = key_i; dst = xk;    base = 4608; }
  const size_t i = ((size_t)(bid - base) * 256 + tid) * 8;
  *reinterpret_cast<bf16x8*>(dst + i) = cvt8(src + i);
}

// ---------------------------------------------------------------------------
// vmT[bh][d][m] = v_mem[m][b][h*64+d] via LDS transpose.
// 256 blocks = (bh, mc): 64x64 tile. Coalesced 256B row reads, 128B row
// writes. LDS stride 65 -> bank (m+d)%32, 2-way aliasing only (free).
// ---------------------------------------------------------------------------
__global__ __launch_bounds__(256) void vmt_kernel(
    const float* __restrict__ v_mem, bf16* __restrict__ vmT) {
  __shared__ float sm[64][65];
  const int bid = blockIdx.x;
  const int bh = bid >> 2, mc = bid & 3;
  const int b = bh >> 4, h = bh & 15;
  const int m0 = mc * 64;
  const int tid = threadIdx.x;
  const int d = tid & 63, mi = tid >> 6;
#pragma unroll
  for (int mm = mi; mm < 64; mm += 4)
    sm[mm][d] = v_mem[((size_t)(m0 + mm) * BB + b) * EE + h * 64 + d];
  __syncthreads();
  const int mw = tid & 63, di = tid >> 6;
#pragma unroll
  for (int dd = di; dd < 64; dd += 4)
    vmT[((size_t)bh * HD + dd) * MM + m0 + mw] = (bf16)sm[mw][dd];
}

// ---------------------------------------------------------------------------
// In-place interleaved rotary on qh and kh (pure HBM-bound elementwise).
// ---------------------------------------------------------------------------
__global__ __launch_bounds__(256) void rope_kernel(
    bf16* __restrict__ qh, bf16* __restrict__ kh,
    const float* __restrict__ q_pe, const float* __restrict__ kv_pe) {
  const size_t CP = (size_t)BH * LL * HD / 8;  // 524288 chunks per tensor
  size_t gi = (size_t)blockIdx.x * 256 + threadIdx.x;
  bf16* x; const float* pe;
  if (gi < CP) { x = qh; pe = q_pe; }
  else         { x = kh; pe = kv_pe; gi -= CP; }
  const int d8 = gi & 7;
  const int t  = (int)((gi >> 3) & (LL - 1));
  const int bh = (int)(gi >> 13);
  const int b = bh >> 4, h = bh & 15;
  bf16* xp = x + gi * 8;
  const float* pp = pe + (((size_t)b * LL + t) * EE + h * 64 + d8 * 8) * 2;
  bf16x8 v = *reinterpret_cast<const bf16x8*>(xp);
  const f32x4 p0 = *reinterpret_cast<const f32x4*>(pp);
  const f32x4 p1 = *reinterpret_cast<const f32x4*>(pp + 4);
  const f32x4 p2 = *reinterpret_cast<const f32x4*>(pp + 8);
  const f32x4 p3 = *reinterpret_cast<const f32x4*>(pp + 12);
  float cs[8], sn[8], xv[8];
  cs[0]=p0[0]; sn[0]=p0[1]; cs[1]=p0[2]; sn[1]=p0[3];
  cs[2]=p1[0]; sn[2]=p1[1]; cs[3]=p1[2]; sn[3]=p1[3];
  cs[4]=p2[0]; sn[4]=p2[1]; cs[5]=p2[2]; sn[5]=p2[3];
  cs[6]=p3[0]; sn[6]=p3[1]; cs[7]=p3[2]; sn[7]=p3[3];
#pragma unroll
  for (int j = 0; j < 8; ++j) xv[j] = (float)v[j];
  bf16x8 o;
#pragma unroll
  for (int j = 0; j < 8; j += 2) {
    o[j]     = (bf16)(xv[j]     * cs[j]     - xv[j + 1] * sn[j]);
    o[j + 1] = (bf16)(xv[j + 1] * cs[j + 1] + xv[j]     * sn[j + 1]);
  }
  *reinterpret_cast<bf16x8*>(xp) = o;
}

// ---------------------------------------------------------------------------
// Fused q/k/v projection GEMM: BM=BN=128, 768 blocks, 4 waves 2x2, dbuf LDS.
// which 0/1: out[rowg=t*4+b][col=e_out] = X W^T  -> qh/kh[bh][t][d]
// which 2  : TRANSPOSED product V^T = W_v X_v^T (A=W_v rows=e_out,
//            B=xv b-major rows=b*SS+s) -> vhT[bh][d][s], s-coalesced writes.
// ---------------------------------------------------------------------------
__global__ __launch_bounds__(256) void gemm3_kernel(
    const bf16* __restrict__ xq, const bf16* __restrict__ xk,
    const bf16* __restrict__ xv, const bf16* __restrict__ wb,
    const float* __restrict__ ipb, bf16* __restrict__ qh,
    bf16* __restrict__ kh, bf16* __restrict__ vhT) {
  __shared__ bf16 As[2][4096];
  __shared__ bf16 Bs[2][4096];
  const int tid = threadIdx.x;
  const int wv = tid >> 6, lane = tid & 63;
  const int lrow = lane & 15, lkg = lane >> 4;
  const int wr = wv >> 1, wc = wv & 1;
  const int n = (blockIdx.x & 7) * 96 + (blockIdx.x >> 3);  // XCD-chunked
  const int which = n >> 8, sub = n & 255;

  const bf16* X; const bf16* W;
  int rowA0, colB0;
  if (which == 2) {
    X = wb + 2 * (size_t)EE * EE;       // W_v (1024 x 1024)
    W = xv;                              // xv b-major (4096 x 1024)
    rowA0 = (sub & 7) * 128;             // e_out tile (8 tiles)
    colB0 = (sub >> 3) * 128;            // b*SS+s tile (32 tiles)
  } else {
    X = (which == 0) ? xq : xk;
    W = wb + (size_t)which * EE * EE;
    rowA0 = (sub >> 3) * 128;
    colB0 = (sub & 7) * 128;
  }

  const f32x4 zero = {0.f, 0.f, 0.f, 0.f};
  f32x4 acc[4][4];
#pragma unroll
  for (int i = 0; i < 4; ++i)
#pragma unroll
    for (int j = 0; j < 4; ++j) acc[i][j] = zero;

  auto stage = [&](int buf, int k0) {
#pragma unroll
    for (int t = 0; t < 2; ++t) {
      const int i = wv * 2 + t;
      const int slot = i * 64 + lane;
      const int srow = slot & 127, sk8 = slot >> 7;
      gload_lds16(X + (size_t)(rowA0 + srow) * EE + k0 + sk8 * 8, &As[buf][i * 512]);
      gload_lds16(W + (size_t)(colB0 + srow) * EE + k0 + sk8 * 8, &Bs[buf][i * 512]);
    }
  };

  stage(0, 0);
  __syncthreads();
  for (int ks = 0; ks < 32; ++ks) {
    const int buf = ks & 1;
    if (ks < 31) stage(buf ^ 1, (ks + 1) * 32);
    bf16x8 av[4], bv[4];
#pragma unroll
    for (int i = 0; i < 4; ++i) {
      av[i] = *reinterpret_cast<const bf16x8*>(&As[buf][lkg * 1024 + (wr * 64 + i * 16 + lrow) * 8]);
      bv[i] = *reinterpret_cast<const bf16x8*>(&Bs[buf][lkg * 1024 + (wc * 64 + i * 16 + lrow) * 8]);
    }
#pragma unroll
    for (int mt = 0; mt < 4; ++mt)
#pragma unroll
      for (int nt = 0; nt < 4; ++nt)
        acc[mt][nt] = mfma16(av[mt], bv[nt], acc[mt][nt]);
    __syncthreads();
  }

  if (which == 2) {
    // rows = e_out (h*64+d), cols = b*SS+s; bias indexed by ROW.
#pragma unroll
    for (int mt = 0; mt < 4; ++mt) {
#pragma unroll
      for (int r = 0; r < 4; ++r) {
        const int rowg = rowA0 + wr * 64 + mt * 16 + lkg * 4 + r;
        const float bs = ipb[2 * EE + rowg];
        const int h = rowg >> 6, d = rowg & 63;
#pragma unroll
        for (int nt = 0; nt < 4; ++nt) {
          const int c = colB0 + wc * 64 + nt * 16 + lrow;
          const int b = c >> 10, s = c & (SS - 1);
          vhT[(((size_t)(b * HH + h)) * HD + d) * SS + s] = (bf16)(acc[mt][nt][r] + bs);
        }
      }
    }
  } else {
#pragma unroll
    for (int nt = 0; nt < 4; ++nt) {
      const int col = colB0 + wc * 64 + nt * 16 + lrow;
      const float bs = ipb[which * EE + col];
      const int h = col >> 6, d = col & 63;
#pragma unroll
      for (int mt = 0; mt < 4; ++mt) {
#pragma unroll
        for (int r = 0; r < 4; ++r) {
          const int rowg = rowA0 + wr * 64 + mt * 16 + lkg * 4 + r;
          const int t = rowg >> 2;
          const int b = rowg & 3;
          float v = acc[mt][nt][r] + bs;
          if (which == 0) v *= 0.125f;
          const int bh = b * HH + h;
          if (which == 1)
            kh[((size_t)bh * LL + t) * HD + d] = (bf16)v;
          else
            qh[((size_t)bh * LL + t) * HD + d] = (bf16)v;
        }
      }
    }
  }
}

// ---------------------------------------------------------------------------
// Out-projection GEMM: BM=128, BN=64 -> 512 blocks. Writes f32 d_out.
// ---------------------------------------------------------------------------
__global__ __launch_bounds__(256) void gemm_out_kernel(
    const bf16* __restrict__ Xb, const bf16* __restrict__ W,
    const float* __restrict__ bias, float* __restrict__ outf) {
  __shared__ bf16 As[2][4096];
  __shared__ bf16 Bs[2][2048];
  const int tid = threadIdx.x;
  const int wv = tid >> 6, lane = tid & 63;
  const int lrow = lane & 15, lkg = lane >> 4;
  const int wr = wv >> 1, wc = wv & 1;
  const int n = (blockIdx.x & 7) * 64 + (blockIdx.x >> 3);
  const int rowt = n >> 4, colt = n & 15;
  const int rowA0 = rowt * 128, colB0 = colt * 64;

  const f32x4 zero = {0.f, 0.f, 0.f, 0.f};
  f32x4 acc[4][2];
#pragma unroll
  for (int i = 0; i < 4; ++i)
#pragma unroll
    for (int j = 0; j < 2; ++j) acc[i][j] = zero;

  auto stage = [&](int buf, int k0) {
#pragma unroll
    for (int t = 0; t < 2; ++t) {
      const int i = wv * 2 + t;
      const int slot = i * 64 + lane;
      const int srow = slot & 127, sk8 = slot >> 7;
      gload_lds16(Xb + (size_t)(rowA0 + srow) * EE + k0 + sk8 * 8, &As[buf][i * 512]);
    }
    {
      const int slot = wv * 64 + lane;
      const int srow = slot & 63, sk8 = slot >> 6;
      gload_lds16(W + (size_t)(colB0 + srow) * EE + k0 + sk8 * 8, &Bs[buf][wv * 512]);
    }
  };

  stage(0, 0);
  __syncthreads();
  for (int ks = 0; ks < 32; ++ks) {
    const int buf = ks & 1;
    if (ks < 31) stage(buf ^ 1, (ks + 1) * 32);
    bf16x8 av[4], bv[2];
#pragma unroll
    for (int i = 0; i < 4; ++i)
      av[i] = *reinterpret_cast<const bf16x8*>(&As[buf][lkg * 1024 + (wr * 64 + i * 16 + lrow) * 8]);
#pragma unroll
    for (int j = 0; j < 2; ++j)
      bv[j] = *reinterpret_cast<const bf16x8*>(&Bs[buf][lkg * 512 + (wc * 32 + j * 16 + lrow) * 8]);
#pragma unroll
    for (int mt = 0; mt < 4; ++mt)
#pragma unroll
      for (int nt = 0; nt < 2; ++nt)
        acc[mt][nt] = mfma16(av[mt], bv[nt], acc[mt][nt]);
    __syncthreads();
  }

#pragma unroll
  for (int nt = 0; nt < 2; ++nt) {
    const int col = colB0 + wc * 32 + nt * 16 + lrow;
    const float bs = bias[col];
#pragma unroll
    for (int mt = 0; mt < 4; ++mt)
#pragma unroll
      for (int r = 0; r < 4; ++r) {
        const int rowg = rowA0 + wr * 64 + mt * 16 + lkg * 4 + r;
        outf[(size_t)rowg * EE + col] = acc[mt][nt][r] + bs;
      }
  }
}

// ---------------------------------------------------------------------------
// Column softmax stats over L for each (bh, s): moff = m + ln(sum exp(sc-m)).
// ---------------------------------------------------------------------------
__global__ __launch_bounds__(256) void stats_kernel(
    const bf16* __restrict__ qh, const bf16* __restrict__ kh,
    float* __restrict__ moff) {
  __shared__ float sm[4][4][16], sd[4][4][16];
  const int tid = threadIdx.x;
  const int wv = tid >> 6, lane = tid & 63;
  const int lrow = lane & 15, lkg = lane >> 4;
  const int n = blockIdx.x;
  const int j = n >> 3;
  const int bh = (n & 7) + 8 * (j >> 4);
  const int s0 = (j & 15) * 64;

  bf16x8 b0[4], b1[4];
#pragma unroll
  for (int ct = 0; ct < 4; ++ct) {
    const bf16* kp = kh + ((size_t)bh * SS + s0 + ct * 16 + lrow) * HD + lkg * 8;
    b0[ct] = *reinterpret_cast<const bf16x8*>(kp);
    b1[ct] = *reinterpret_cast<const bf16x8*>(kp + 32);
  }

  const f32x4 zero = {0.f, 0.f, 0.f, 0.f};
  float m[4] = {-1e30f, -1e30f, -1e30f, -1e30f};
  float d[4] = {0.f, 0.f, 0.f, 0.f};
  const bf16* qbase = qh + ((size_t)bh * LL + wv * 256 + lrow) * HD + lkg * 8;
  for (int i = 0; i < 16; ++i) {
    bf16x8 a0 = *reinterpret_cast<const bf16x8*>(qbase + (size_t)i * 16 * HD);
    bf16x8 a1 = *reinterpret_cast<const bf16x8*>(qbase + (size_t)i * 16 * HD + 32);
#pragma unroll
    for (int ct = 0; ct < 4; ++ct) {
      f32x4 c = zero;
      c = mfma16(a0, b0[ct], c);
      c = mfma16(a1, b1[ct], c);
      float tm = fmaxf(fmaxf(c[0], c[1]), fmaxf(c[2], c[3]));
      float nm = fmaxf(m[ct], tm);
      float dd = d[ct] * __expf(m[ct] - nm);
#pragma unroll
      for (int r = 0; r < 4; ++r) dd += __expf(c[r] - nm);
      d[ct] = dd; m[ct] = nm;
    }
  }
#pragma unroll
  for (int off = 16; off < 64; off <<= 1) {
#pragma unroll
    for (int ct = 0; ct < 4; ++ct) {
      float mo = __shfl_xor(m[ct], off);
      float dd = __shfl_xor(d[ct], off);
      float nm = fmaxf(m[ct], mo);
      d[ct] = d[ct] * __expf(m[ct] - nm) + dd * __expf(mo - nm);
      m[ct] = nm;
    }
  }
  if (lkg == 0) {
#pragma unroll
    for (int ct = 0; ct < 4; ++ct) { sm[wv][ct][lrow] = m[ct]; sd[wv][ct][lrow] = d[ct]; }
  }
  __syncthreads();
  if (wv == 0 && lkg == 0) {
#pragma unroll
    for (int ct = 0; ct < 4; ++ct) {
      float mm = sm[0][ct][lrow], dd = sd[0][ct][lrow];
#pragma unroll
      for (int w = 1; w < 4; ++w) {
        float mo = sm[w][ct][lrow], d2 = sd[w][ct][lrow];
        float nm = fmaxf(mm, mo);
        dd = dd * __expf(mm - nm) + d2 * __expf(mo - nm);
        mm = nm;
      }
      moff[(size_t)bh * SS + s0 + ct * 16 + lrow] = mm + __logf(dd);
    }
  }
}

// colsum_v[bh][d] = sum_s vhT[bh][d][s]
__global__ __launch_bounds__(64) void colsum_kernel(
    const bf16* __restrict__ vhT, float* __restrict__ colsum) {
  const int bh = blockIdx.x, d = blockIdx.y, lane = threadIdx.x;
  const bf16* p = vhT + ((size_t)bh * HD + d) * SS;
  float s = 0.f;
  for (int i = lane; i < SS; i += 64) s += (float)p[i];
#pragma unroll
  for (int off = 32; off; off >>= 1) s += __shfl_xor(s, off);
  if (lane == 0) colsum[bh * HD + d] = s;
}

// ---------------------------------------------------------------------------
// Attention v3 (proven best): block = 4 waves x 32 q-rows (128 rows) of one
// bh. K/V tiles staged in LDS (global_load_lds), shared by 4 waves, dbuf.
// Row-sum via ones-MFMA. XCD-grouped.
// ---------------------------------------------------------------------------
__global__ __launch_bounds__(256) void attn_kernel(
    const bf16* __restrict__ qh, const bf16* __restrict__ kh,
    const bf16* __restrict__ vhT, const bf16* __restrict__ vmT,
    const bf16* __restrict__ k_mem, const float* __restrict__ gate_w,
    const float* __restrict__ moff, const float* __restrict__ colsum,
    bf16* __restrict__ attn2) {
  __shared__ bf16 Ks[2][2048];
  __shared__ bf16 Vs[2][2048];
  __shared__ bf16 wt[4][32][40];
  const int tid = threadIdx.x;
  const int wv = tid >> 6, lane = tid & 63;
  const int lrow = lane & 15, lkg = lane >> 4;
  const int bid = blockIdx.x;
  const int bh = (bid & 7) + 8 * (bid >> 6);
  const int b = bh >> 4, h = bh & 15;
  const int l0 = ((bid >> 3) & 7) * 128 + wv * 32;

  bf16x8 aq[2][2];
#pragma unroll
  for (int rt = 0; rt < 2; ++rt) {
    const bf16* qp = qh + ((size_t)bh * LL + l0 + rt * 16 + lrow) * HD + lkg * 8;
    aq[rt][0] = *reinterpret_cast<const bf16x8*>(qp);
    aq[rt][1] = *reinterpret_cast<const bf16x8*>(qp + 32);
  }

  bf16x8 ones;
#pragma unroll
  for (int i = 0; i < 8; ++i) ones[i] = (bf16)1.0f;

  const f32x4 zero = {0.f, 0.f, 0.f, 0.f};
  f32x4 acc[2][4], accm[2][4], racc[2];
#pragma unroll
  for (int rt = 0; rt < 2; ++rt) {
    racc[rt] = zero;
#pragma unroll
    for (int i = 0; i < 4; ++i) { acc[rt][i] = zero; accm[rt][i] = zero; }
  }

  const int srow = lane & 31, sk8h = lane >> 5;  // staging decode
  auto stageK = [&](int buf, int s0) {
    gload_lds16(kh + ((size_t)bh * SS + s0 + srow) * HD + (wv * 2 + sk8h) * 8,
                &Ks[buf][wv * 512]);
  };
  auto stageV = [&](int buf, int s0) {
    gload_lds16(vhT + ((size_t)bh * HD + lane) * SS + s0 + wv * 8,
                &Vs[buf][wv * 512]);
  };
  auto stageKM = [&](int buf, int m0) {
    gload_lds16(k_mem + ((size_t)(m0 + srow) * BB + b) * EE + h * 64 + (wv * 2 + sk8h) * 8,
                &Ks[buf][wv * 512]);
  };
  auto stageVM = [&](int buf, int m0) {
    gload_lds16(vmT + ((size_t)bh * HD + lane) * MM + m0 + wv * 8,
                &Vs[buf][wv * 512]);
  };
  auto kfrag = [&](int buf, int t, int half) {
    return *reinterpret_cast<const bf16x8*>(&Ks[buf][((half * 4 + lkg) * 32 + t * 16 + lrow) * 8]);
  };
  auto vfrag = [&](int buf, int dt) {
    return *reinterpret_cast<const bf16x8*>(&Vs[buf][(lkg * 64 + dt * 16 + lrow) * 8]);
  };

  // ---- main attention ----
  stageK(0, 0); stageV(0, 0);
  __syncthreads();
  for (int s0 = 0; s0 < SS; s0 += 32) {
    const int buf = (s0 >> 5) & 1;
    if (s0 + 32 < SS) { stageK(buf ^ 1, s0 + 32); stageV(buf ^ 1, s0 + 32); }
    bf16x8 kf[2][2];
#pragma unroll
    for (int t = 0; t < 2; ++t) { kf[t][0] = kfrag(buf, t, 0); kf[t][1] = kfrag(buf, t, 1); }
    f32x4 sc[2][2];
#pragma unroll
    for (int rt = 0; rt < 2; ++rt)
#pragma unroll
      for (int t = 0; t < 2; ++t) {
        f32x4 c = zero;
        c = mfma16(aq[rt][0], kf[t][0], c);
        c = mfma16(aq[rt][1], kf[t][1], c);
        sc[rt][t] = c;
      }
#pragma unroll
    for (int t = 0; t < 2; ++t) {
      const float mo = moff[(size_t)bh * SS + s0 + t * 16 + lrow];
#pragma unroll
      for (int rt = 0; rt < 2; ++rt)
#pragma unroll
        for (int r = 0; r < 4; ++r)
          wt[wv][rt * 16 + lkg * 4 + r][t * 16 + lrow] = (bf16)__expf(sc[rt][t][r] - mo);
    }
    bf16x8 aw[2];
#pragma unroll
    for (int rt = 0; rt < 2; ++rt) {
      aw[rt] = *reinterpret_cast<const bf16x8*>(&wt[wv][rt * 16 + lrow][lkg * 8]);
      racc[rt] = mfma16(aw[rt], ones, racc[rt]);
    }
#pragma unroll
    for (int dt = 0; dt < 4; ++dt) {
      bf16x8 bv = vfrag(buf, dt);
#pragma unroll
      for (int rt = 0; rt < 2; ++rt) acc[rt][dt] = mfma16(aw[rt], bv, acc[rt][dt]);
    }
    __syncthreads();
  }

  // ---- memory attention pass 1: per-row online stats ----
  float mx[2][4], dn[2][4];
#pragma unroll
  for (int rt = 0; rt < 2; ++rt)
#pragma unroll
    for (int r = 0; r < 4; ++r) { mx[rt][r] = -1e30f; dn[rt][r] = 0.f; }
  stageKM(0, 0);
  __syncthreads();
  for (int m0 = 0; m0 < MM; m0 += 32) {
    const int buf = (m0 >> 5) & 1;
    if (m0 + 32 < MM) stageKM(buf ^ 1, m0 + 32);
    bf16x8 kf[2][2];
#pragma unroll
    for (int t = 0; t < 2; ++t) { kf[t][0] = kfrag(buf, t, 0); kf[t][1] = kfrag(buf, t, 1); }
#pragma unroll
    for (int rt = 0; rt < 2; ++rt)
#pragma unroll
      for (int t = 0; t < 2; ++t) {
        f32x4 c = zero;
        c = mfma16(aq[rt][0], kf[t][0], c);
        c = mfma16(aq[rt][1], kf[t][1], c);
#pragma unroll
        for (int r = 0; r < 4; ++r) {
          float nm = fmaxf(mx[rt][r], c[r]);
          dn[rt][r] = dn[rt][r] * __expf(mx[rt][r] - nm) + __expf(c[r] - nm);
          mx[rt][r] = nm;
        }
      }
    __syncthreads();
  }
#pragma unroll
  for (int off = 1; off < 16; off <<= 1) {
#pragma unroll
    for (int rt = 0; rt < 2; ++rt)
#pragma unroll
      for (int r = 0; r < 4; ++r) {
        float mo = __shfl_xor(mx[rt][r], off);
        float dd = __shfl_xor(dn[rt][r], off);
        float nm = fmaxf(mx[rt][r], mo);
        dn[rt][r] = dn[rt][r] * __expf(mx[rt][r] - nm) + dd * __expf(mo - nm);
        mx[rt][r] = nm;
      }
  }
#pragma unroll
  for (int rt = 0; rt < 2; ++rt)
#pragma unroll
    for (int r = 0; r < 4; ++r) dn[rt][r] = 1.f / dn[rt][r];

  // ---- memory attention pass 2: weights + PV ----
  stageKM(0, 0); stageVM(0, 0);
  __syncthreads();
  for (int m0 = 0; m0 < MM; m0 += 32) {
    const int buf = (m0 >> 5) & 1;
    if (m0 + 32 < MM) { stageKM(buf ^ 1, m0 + 32); stageVM(buf ^ 1, m0 + 32); }
    bf16x8 kf[2][2];
#pragma unroll
    for (int t = 0; t < 2; ++t) { kf[t][0] = kfrag(buf, t, 0); kf[t][1] = kfrag(buf, t, 1); }
#pragma unroll
    for (int rt = 0; rt < 2; ++rt)
#pragma unroll
      for (int t = 0; t < 2; ++t) {
        f32x4 c = zero;
        c = mfma16(aq[rt][0], kf[t][0], c);
        c = mfma16(aq[rt][1], kf[t][1], c);
#pragma unroll
        for (int r = 0; r < 4; ++r)
          wt[wv][rt * 16 + lkg * 4 + r][t * 16 + lrow] = (bf16)(__expf(c[r] - mx[rt][r]) * dn[rt][r]);
      }
    bf16x8 aw[2];
#pragma unroll
    for (int rt = 0; rt < 2; ++rt)
      aw[rt] = *reinterpret_cast<const bf16x8*>(&wt[wv][rt * 16 + lrow][lkg * 8]);
#pragma unroll
    for (int dt = 0; dt < 4; ++dt) {
      bf16x8 bv = vfrag(buf, dt);
#pragma unroll
      for (int rt = 0; rt < 2; ++rt) accm[rt][dt] = mfma16(aw[rt], bv, accm[rt][dt]);
    }
    __syncthreads();
  }

  // ---- epilogue: renormalize, gate, store ----
  float g = gate_w[h];
  g = 1.f / (1.f + __expf(-g));

#pragma unroll
  for (int dt = 0; dt < 4; ++dt) {
    const int d = dt * 16 + lrow;
    const float cv = colsum[bh * HD + d] * 1e-8f;
#pragma unroll
    for (int rt = 0; rt < 2; ++rt)
#pragma unroll
      for (int r = 0; r < 4; ++r) {
        const int lg = l0 + rt * 16 + lkg * 4 + r;
        const float den = racc[rt][r] + (float)SS * 1e-8f;
        const float amain = (acc[rt][dt][r] + cv) / den;
        const float v = g * accm[rt][dt][r] + (1.f - g) * amain;
        attn2[((size_t)lg * BB + b) * EE + h * 64 + d] = (bf16)v;
      }
  }
}

// ---------------------------------------------------------------------------
extern "C" void kernel_launch(void* const* d_in, const int* in_sizes, int n_in,
                              void* d_out, int out_size, void* d_ws, size_t ws_size,
                              hipStream_t stream) {
  const float* query = (const float*)d_in[0];
  const float* key_i = (const float*)d_in[1];
  const float* value = (const float*)d_in[2];
  const float* ipw   = (const float*)d_in[3];
  const float* ipb   = (const float*)d_in[4];
  const float* opw   = (const float*)d_in[5];
  const float* opb   = (const float*)d_in[6];
  const float* q_pe  = (const float*)d_in[7];
  const float* kv_pe = (const float*)d_in[8];
  const float* k_mem = (const float*)d_in[9];
  const float* v_mem = (const float*)d_in[10];
  const float* gate  = (const float*)d_in[11];

  char* ws = (char*)d_ws;
  bf16* qh    = (bf16*)(ws);                  // 8 MB  (BH, L, HD)
  bf16* kh    = (bf16*)(ws + (8u << 20));     // 8 MB  (BH, S, HD)
  bf16* vhT   = (bf16*)(ws + (16u << 20));    // 8 MB  (BH, HD, S)
  bf16* attn2 = (bf16*)(ws + (24u << 20));    // 8 MB  (L*B, E); xq scratch pre-attn
  bf16* vmT   = (bf16*)(ws + (32u << 20));    // 2 MB  (BH, HD, M)
  float* moff   = (float*)(ws + (34u << 20));                 // 256 KB
  float* colsum = (float*)(ws + (34u << 20) + (1u << 18));    // 16 KB
  bf16* wb    = (bf16*)(ws + (35u << 20));    // 6 MB  (3E, E) bf16
  bf16* opwb  = (bf16*)(ws + (41u << 20));    // 2 MB  (E, E)  bf16
  bf16* kmemb = (bf16*)(ws + (43u << 20));    // 2 MB  (M, B, E) bf16
  bf16* xq = attn2;
  bf16* xk = (bf16*)d_out;
  bf16* xv = (bf16*)d_out + (size_t)SS * BB * EE;  // b-major (B, S, E)

  dim3 blk(256);
  hipLaunchKernelGGL(cvt_all_kernel, dim3(8704), blk, 0, stream, ipw, opw, k_mem,
                     query, key_i, value, wb, opwb, kmemb, xq, xk, xv);
  hipLaunchKernelGGL(vmt_kernel, dim3(256), blk, 0, stream, v_mem, vmT);
  hipLaunchKernelGGL(gemm3_kernel, dim3(768), blk, 0, stream, xq, xk, xv, wb,
                     ipb, qh, kh, vhT);
  hipLaunchKernelGGL(rope_kernel, dim3(4096), blk, 0, stream, qh, kh, q_pe, kv_pe);
  hipLaunchKernelGGL(stats_kernel, dim3(1024), blk, 0, stream, qh, kh, moff);
  hipLaunchKernelGGL(colsum_kernel, dim3(64, 64), dim3(64), 0, stream, vhT, colsum);
  hipLaunchKernelGGL(attn_kernel, dim3(512), blk, 0, stream, qh, kh, vhT, vmT,
                     kmemb, gate, moff, colsum, attn2);
  hipLaunchKernelGGL(gemm_out_kernel, dim3(512), blk, 0, stream, attn2, opwb, opb,
                     (float*)d_out);
}